// Round 2
// baseline (120.269 us; speedup 1.0000x reference)
//
#include <hip/hip_runtime.h>
#include <cstdint>

#define N_NODES 8192
#define DIN 128
#define DOUT 128
#define WORDS_PER_ROW (N_NODES / 32)                 // 256 u32 words per adjacency row
#define MASK_BYTES (N_NODES * WORDS_PER_ROW * 4)     // 8 MB
#define MAXDEG 128                                   // Poisson(32) tail @128: ~1e-18
#define EPS 1e-8f
#define GEMM_ROWS 16

// workspace layout (bytes):
//   [mask 8 MB][cnt 32 KB][dis 32 KB][list 4 MB][z 4 MB]   = 16.1 MB
#define OFF_CNT  (MASK_BYTES)
#define OFF_DIS  (OFF_CNT + N_NODES * 4)
#define OFF_LIST (OFF_DIS + N_NODES * 4)
#define OFF_Z    (OFF_LIST + N_NODES * MAXDEG * 4)
#define ZERO_WORDS ((MASK_BYTES + N_NODES * 4) / 4) // mask + cnt, contiguous

// ---------------------------------------------------------------------------
// Kernel 1: zero mask + cnt with uint4 stores (replaces hipMemsetAsync).
// ---------------------------------------------------------------------------
__global__ __launch_bounds__(256) void gcn_fill(uint32_t* __restrict__ ws) {
    int idx = blockIdx.x * blockDim.x + threadIdx.x;   // one uint4 per thread
    ((uint4*)ws)[idx] = make_uint4(0u, 0u, 0u, 0u);
}

// ---------------------------------------------------------------------------
// Kernel 2: scatter-set bits + build deduped CSR in one pass.
// First setter of a bit appends dst to row src's list and bumps cnt[src].
// idx < E: edge (src=ei[idx], dst=ei[E+idx]); idx >= E: self loop.
// ---------------------------------------------------------------------------
__global__ __launch_bounds__(256) void gcn_scatter(const int* __restrict__ ei, int E,
                                                   uint32_t* __restrict__ mask,
                                                   int* __restrict__ cnt,
                                                   int* __restrict__ list) {
    int idx = blockIdx.x * blockDim.x + threadIdx.x;
    if (idx >= E + N_NODES) return;
    int src, dst;
    if (idx < E) {
        src = ei[idx];
        dst = ei[E + idx];
    } else {
        src = dst = idx - E;
    }
    uint32_t bit = 1u << (dst & 31);
    uint32_t old = atomicOr(&mask[src * WORDS_PER_ROW + (dst >> 5)], bit);
    if (!(old & bit)) {
        int pos = atomicAdd(&cnt[src], 1);
        if (pos < MAXDEG) list[src * MAXDEG + pos] = dst;
    }
}

// ---------------------------------------------------------------------------
// Kernel 3: z = x @ W^T. Thread t owns output column t for GEMM_ROWS rows;
// x tile in LDS (contiguous b128 broadcast reads), W rows streamed as float4
// (64 KB, L1/L2 resident). Blocks 0..63 also compute dis = rsqrt(cnt+eps)
// (free rider: saves a separate launch; cnt is ready, agg runs after us).
// ---------------------------------------------------------------------------
__global__ __launch_bounds__(128) void gcn_xw(const float* __restrict__ x,
                                              const float* __restrict__ W,
                                              float* __restrict__ z,
                                              const int* __restrict__ cnt,
                                              float* __restrict__ dis) {
    int t = threadIdx.x;            // 0..127 = output column
    if (blockIdx.x < N_NODES / 128) {
        int i = blockIdx.x * 128 + t;
        dis[i] = rsqrtf((float)cnt[i] + EPS);
    }

    __shared__ float xlds[GEMM_ROWS][DIN];
    int row0 = blockIdx.x * GEMM_ROWS;
    for (int r = 0; r < GEMM_ROWS; r++)
        xlds[r][t] = x[(size_t)(row0 + r) * DIN + t];
    __syncthreads();

    float acc[GEMM_ROWS];
#pragma unroll
    for (int r = 0; r < GEMM_ROWS; r++) acc[r] = 0.f;

    const float* wrow = W + (size_t)t * DIN;
    for (int d = 0; d < DIN; d += 4) {
        float4 wv = *(const float4*)(wrow + d);
#pragma unroll
        for (int r = 0; r < GEMM_ROWS; r++) {
            acc[r] += xlds[r][d + 0] * wv.x + xlds[r][d + 1] * wv.y +
                      xlds[r][d + 2] * wv.z + xlds[r][d + 3] * wv.w;
        }
    }
#pragma unroll
    for (int r = 0; r < GEMM_ROWS; r++)
        z[(size_t)(row0 + r) * DOUT + t] = acc[r];
}

// ---------------------------------------------------------------------------
// Kernel 4: out[i][t] = b[t] + dis[i] * sum_{j in row i} dis[j] * z[j][t]
// One 128-thread block per row. Neighbor list + dis gathered to LDS once,
// then thread t accumulates column t (z reads coalesced 512 B/iter).
// ---------------------------------------------------------------------------
__global__ __launch_bounds__(128) void gcn_agg(const int* __restrict__ cnt,
                                               const int* __restrict__ list,
                                               const float* __restrict__ dis,
                                               const float* __restrict__ z,
                                               const float* __restrict__ bias,
                                               float* __restrict__ out) {
    __shared__ int   nbr[MAXDEG];
    __shared__ float dls[MAXDEG];
    int i = blockIdx.x;
    int t = threadIdx.x;            // 0..127
    int n = min(cnt[i], MAXDEG);
    if (t < n) {
        int j = list[i * MAXDEG + t];
        nbr[t] = j;
        dls[t] = dis[j];            // 32 KB table, L1/L2 hot
    }
    __syncthreads();

    float acc = 0.f;
    for (int m = 0; m < n; m++)
        acc += dls[m] * z[(size_t)nbr[m] * DOUT + t];   // LDS broadcast + coalesced z

    out[(size_t)i * DOUT + t] = bias[t] + dis[i] * acc;
}

// ---------------------------------------------------------------------------
extern "C" void kernel_launch(void* const* d_in, const int* in_sizes, int n_in,
                              void* d_out, int out_size, void* d_ws, size_t ws_size,
                              hipStream_t stream) {
    const float* x  = (const float*)d_in[0];
    const int*   ei = (const int*)d_in[1];
    const float* W  = (const float*)d_in[2];
    const float* b  = (const float*)d_in[3];
    float* out = (float*)d_out;

    int E = in_sizes[1] / 2;

    uint32_t* mask = (uint32_t*)d_ws;
    int*   cnt  = (int*)  ((char*)d_ws + OFF_CNT);
    float* dis  = (float*)((char*)d_ws + OFF_DIS);
    int*   list = (int*)  ((char*)d_ws + OFF_LIST);
    float* z    = (float*)((char*)d_ws + OFF_Z);

    // zero mask + cnt (one uint4 per thread)
    gcn_fill<<<ZERO_WORDS / 4 / 256, 256, 0, stream>>>((uint32_t*)d_ws);

    int total = E + N_NODES;
    gcn_scatter<<<(total + 255) / 256, 256, 0, stream>>>(ei, E, mask, cnt, list);

    gcn_xw<<<N_NODES / GEMM_ROWS, 128, 0, stream>>>(x, W, z, cnt, dis);

    gcn_agg<<<N_NODES, 128, 0, stream>>>(cnt, list, dis, z, b, out);
}

// Round 3
// 114.243 us; speedup vs baseline: 1.0527x; 1.0527x over previous
//
#include <hip/hip_runtime.h>
#include <cstdint>

#define N_NODES 8192
#define DIN 128
#define DOUT 128
#define WORDS_PER_ROW (N_NODES / 32)             // 256 u32 words per adjacency row
#define MASK_WORDS (N_NODES * WORDS_PER_ROW)     // 2M words = 8 MB
#define MAXDEG 128                               // Poisson(32) tail @128: negligible
#define EPS 1e-8f
#define XW_ROWS 32                               // rows per xw block

// workspace layout (bytes): [mask 8MB][cnt 32KB][list(u16) 2MB][z16 2MB]
#define OFF_CNT  (MASK_WORDS * 4)
#define OFF_LIST (OFF_CNT + N_NODES * 4)
#define OFF_Z16  (OFF_LIST + N_NODES * MAXDEG * 2)

static __device__ __forceinline__ uint16_t f2bf(float f) {
    uint32_t u = __float_as_uint(f);
    return (uint16_t)((u + 0x7fffu + ((u >> 16) & 1u)) >> 16);   // RNE
}
static __device__ __forceinline__ float bf2f(uint32_t bits16) {
    return __uint_as_float(bits16 << 16);
}

// ---------------------------------------------------------------------------
// Kernel 1: init mask (zeros + pre-set diagonal/self-loop bits) and cnt = 1.
// One uint4 per thread over [mask | cnt], exact grid.
// ---------------------------------------------------------------------------
__global__ __launch_bounds__(256) void gcn_fill(uint32_t* __restrict__ ws) {
    uint32_t idx = blockIdx.x * 256 + threadIdx.x;     // uint4 index
    uint32_t w0 = idx * 4;
    uint32_t vals[4];
#pragma unroll
    for (int k = 0; k < 4; k++) {
        uint32_t w = w0 + k;
        if (w < MASK_WORDS) {
            uint32_t r = w >> 8;                       // row this word belongs to
            uint32_t diag = (r << 8) + (r >> 5);       // word holding bit (r,r)
            vals[k] = (w == diag) ? (1u << (r & 31)) : 0u;
        } else {
            vals[k] = 1u;                              // cnt init = 1 (self loop)
        }
    }
    ((uint4*)ws)[idx] = make_uint4(vals[0], vals[1], vals[2], vals[3]);
}

// ---------------------------------------------------------------------------
// Kernel 2 (fused): blocks [0,sb): dedup-scatter edges into bitmask + CSR.
//                   blocks [sb,..): z16 = bf16(x @ W^T), 32 rows per block.
// The two halves are independent; co-resident waves overlap atomic latency
// (scatter) with VALU work (xw).
// ---------------------------------------------------------------------------
__global__ __launch_bounds__(256) void gcn_mid(const int* __restrict__ ei, int E, int sb,
                                               uint32_t* __restrict__ mask,
                                               int* __restrict__ cnt,
                                               uint16_t* __restrict__ list,
                                               const float* __restrict__ x,
                                               const float* __restrict__ W,
                                               uint16_t* __restrict__ z16) {
    if ((int)blockIdx.x < sb) {
        int idx = blockIdx.x * 256 + threadIdx.x;
        if (idx >= E) return;
        int src = ei[idx];
        int dst = ei[E + idx];
        uint32_t bit = 1u << (dst & 31);
        uint32_t old = atomicOr(&mask[src * WORDS_PER_ROW + (dst >> 5)], bit);
        if (!(old & bit)) {                            // first setter appends
            int pos = atomicAdd(&cnt[src], 1);         // cnt starts at 1 (self)
            if (pos <= MAXDEG) list[src * MAXDEG + pos - 1] = (uint16_t)dst;
        }
        return;
    }

    // ---- xw half: 256 threads = 2 column-teams of 128; team h does 16 rows
    int bb = blockIdx.x - sb;
    int t = threadIdx.x;
    int col = t & 127;
    int half = t >> 7;
    int row0 = bb * XW_ROWS + half * 16;

    __shared__ float xlds[XW_ROWS][DIN];
    for (int r = 0; r < 16; r++)
        xlds[half * 16 + r][col] = x[(size_t)(row0 + r) * DIN + col];
    __syncthreads();

    float acc[16];
#pragma unroll
    for (int r = 0; r < 16; r++) acc[r] = 0.f;

    const float* wrow = W + (size_t)col * DIN;
    for (int d = 0; d < DIN; d += 4) {
        float4 wv = *(const float4*)(wrow + d);        // L1-broadcast across halves
#pragma unroll
        for (int r = 0; r < 16; r++) {
            const float* xr = &xlds[half * 16 + r][d]; // b128 broadcast read
            acc[r] += xr[0] * wv.x + xr[1] * wv.y + xr[2] * wv.z + xr[3] * wv.w;
        }
    }
#pragma unroll
    for (int r = 0; r < 16; r++)
        z16[(size_t)(row0 + r) * DOUT + col] = f2bf(acc[r]);
}

// ---------------------------------------------------------------------------
// Kernel 3: out[i][c] = b[c] + dis_i * (dis_i*z[i][c] + sum_m dis_j*z[j][c])
// One wave (64 lanes) per row; lane t owns columns {2t, 2t+1} via packed
// uint loads of bf16 z (fully coalesced 256 B/row). dis computed on the fly
// from cnt (L2-hot 32 KB). Output written as float2 (512 B/row).
// ---------------------------------------------------------------------------
__global__ __launch_bounds__(64) void gcn_agg(const int* __restrict__ cnt,
                                              const uint16_t* __restrict__ list,
                                              const uint16_t* __restrict__ z16,
                                              const float* __restrict__ bias,
                                              float* __restrict__ out) {
    __shared__ uint16_t snbr[MAXDEG];
    __shared__ float    sdls[MAXDEG];
    int i = blockIdx.x;
    int t = threadIdx.x;                               // 0..63
    int deg = cnt[i];                                  // includes self
    int nl = min(deg - 1, MAXDEG);                     // list entries (non-self)

    for (int m = t; m < nl; m += 64) {
        int j = list[i * MAXDEG + m];
        snbr[m] = (uint16_t)j;
        sdls[m] = rsqrtf((float)cnt[j] + EPS);
    }
    float di = rsqrtf((float)deg + EPS);
    __syncthreads();                                   // single wave: cheap

    const uint32_t* zu = (const uint32_t*)z16;
    float a0, a1;
    {   // self term, weight di
        uint32_t u = zu[(size_t)i * 64 + t];
        a0 = di * bf2f(u & 0xffffu);
        a1 = di * bf2f(u >> 16);
    }
    for (int m = 0; m < nl; m++) {
        int j = snbr[m];
        float dj = sdls[m];
        uint32_t u = zu[(size_t)j * 64 + t];           // coalesced 256 B gather
        a0 += dj * bf2f(u & 0xffffu);
        a1 += dj * bf2f(u >> 16);
    }

    float2 bv = ((const float2*)bias)[t];
    float2 o;
    o.x = bv.x + di * a0;
    o.y = bv.y + di * a1;
    ((float2*)out)[(size_t)i * 64 + t] = o;
}

// ---------------------------------------------------------------------------
extern "C" void kernel_launch(void* const* d_in, const int* in_sizes, int n_in,
                              void* d_out, int out_size, void* d_ws, size_t ws_size,
                              hipStream_t stream) {
    const float* x  = (const float*)d_in[0];
    const int*   ei = (const int*)d_in[1];
    const float* W  = (const float*)d_in[2];
    const float* b  = (const float*)d_in[3];
    float* out = (float*)d_out;

    int E = in_sizes[1] / 2;

    uint32_t* mask = (uint32_t*)d_ws;
    int*      cnt  = (int*)     ((char*)d_ws + OFF_CNT);
    uint16_t* list = (uint16_t*)((char*)d_ws + OFF_LIST);
    uint16_t* z16  = (uint16_t*)((char*)d_ws + OFF_Z16);

    // init mask (+diagonal) and cnt=1
    int fill_u4 = (MASK_WORDS + N_NODES) / 4;
    gcn_fill<<<fill_u4 / 256, 256, 0, stream>>>((uint32_t*)d_ws);

    // fused scatter + xw
    int sb = (E + 255) / 256;                          // scatter blocks
    int xb = N_NODES / XW_ROWS;                        // 256 xw blocks
    gcn_mid<<<sb + xb, 256, 0, stream>>>(ei, E, sb, mask, cnt, list, x, W, z16);

    gcn_agg<<<N_NODES, 64, 0, stream>>>(cnt, list, z16, b, out);
}

// Round 4
// 108.539 us; speedup vs baseline: 1.1081x; 1.0525x over previous
//
#include <hip/hip_runtime.h>
#include <cstdint>

#define N_NODES 8192
#define DIN 128
#define DOUT 128
#define WORDS_PER_ROW (N_NODES / 32)             // 256 u32 words per adjacency row
#define MASK_WORDS (N_NODES * WORDS_PER_ROW)     // 2M words = 8 MB
#define MAXDEG 128                               // Poisson(32): P(deg>128) ~ 1e-18
#define EPS 1e-8f
#define XW_ROWS 32                               // rows per xw block

// workspace layout (bytes): [mask 8MB][dis 32KB][deg 32KB][list(u16) 2MB][z16 2MB]
#define OFF_DIS  (MASK_WORDS * 4)
#define OFF_DEG  (OFF_DIS + N_NODES * 4)
#define OFF_LIST (OFF_DEG + N_NODES * 4)
#define OFF_Z16  (OFF_LIST + N_NODES * MAXDEG * 2)

static __device__ __forceinline__ uint16_t f2bf(float f) {
    uint32_t u = __float_as_uint(f);
    return (uint16_t)((u + 0x7fffu + ((u >> 16) & 1u)) >> 16);   // RNE
}
static __device__ __forceinline__ float bf2f(uint32_t bits16) {
    return __uint_as_float(bits16 << 16);
}

// ---------------------------------------------------------------------------
// Kernel 1: zero the mask with the diagonal (self-loop) bits pre-set.
// One uint4 per thread, exact grid over the 8 MB mask.
// ---------------------------------------------------------------------------
__global__ __launch_bounds__(256) void gcn_fill(uint32_t* __restrict__ mask) {
    uint32_t idx = blockIdx.x * 256 + threadIdx.x;     // uint4 index
    uint32_t w0 = idx * 4;
    uint32_t vals[4];
#pragma unroll
    for (int k = 0; k < 4; k++) {
        uint32_t w = w0 + k;
        uint32_t r = w >> 8;                           // row of this word
        uint32_t diag = (r << 8) + (r >> 5);           // word holding bit (r,r)
        vals[k] = (w == diag) ? (1u << (r & 31)) : 0u;
    }
    ((uint4*)mask)[idx] = make_uint4(vals[0], vals[1], vals[2], vals[3]);
}

// ---------------------------------------------------------------------------
// Kernel 2 (fused): blocks [0,sb): FIRE-AND-FORGET atomicOr scatter (dedup
// happens in the bitmask; no return value -> no wave stall, no cnt hotspot).
// blocks [sb,..): z16 = bf16(x @ W^T), 32 rows per block.
// ---------------------------------------------------------------------------
__global__ __launch_bounds__(256) void gcn_mid(const int* __restrict__ ei, int E, int sb,
                                               uint32_t* __restrict__ mask,
                                               const float* __restrict__ x,
                                               const float* __restrict__ W,
                                               uint16_t* __restrict__ z16) {
    if ((int)blockIdx.x < sb) {
        int idx = blockIdx.x * 256 + threadIdx.x;
        if (idx >= E) return;
        int src = ei[idx];
        int dst = ei[E + idx];
        atomicOr(&mask[src * WORDS_PER_ROW + (dst >> 5)], 1u << (dst & 31));
        return;                                        // result unused -> non-returning atomic
    }

    // ---- xw half: 2 column-teams of 128; team h does 16 rows
    int bb = blockIdx.x - sb;
    int t = threadIdx.x;
    int col = t & 127;
    int half = t >> 7;
    int row0 = bb * XW_ROWS + half * 16;

    __shared__ float xlds[XW_ROWS][DIN];
    for (int r = 0; r < 16; r++)
        xlds[half * 16 + r][col] = x[(size_t)(row0 + r) * DIN + col];
    __syncthreads();

    float acc[16];
#pragma unroll
    for (int r = 0; r < 16; r++) acc[r] = 0.f;

    const float* wrow = W + (size_t)col * DIN;
    for (int d = 0; d < DIN; d += 4) {
        float4 wv = *(const float4*)(wrow + d);
#pragma unroll
        for (int r = 0; r < 16; r++) {
            const float* xr = &xlds[half * 16 + r][d]; // wave-uniform b128 broadcast
            acc[r] += xr[0] * wv.x + xr[1] * wv.y + xr[2] * wv.z + xr[3] * wv.w;
        }
    }
#pragma unroll
    for (int r = 0; r < 16; r++)
        z16[(size_t)(row0 + r) * DOUT + col] = f2bf(acc[r]);
}

// ---------------------------------------------------------------------------
// Kernel 3: extract. One wave per row: coalesced uint4 read of the mask row,
// popcount + wave prefix-scan -> deg, dis, compact u16 neighbor list.
// Zero atomics.
// ---------------------------------------------------------------------------
__global__ __launch_bounds__(256) void gcn_extract(const uint32_t* __restrict__ mask,
                                                   float* __restrict__ dis,
                                                   int* __restrict__ deg,
                                                   uint16_t* __restrict__ list) {
    int row  = blockIdx.x * 4 + (threadIdx.x >> 6);
    int lane = threadIdx.x & 63;
    const uint32_t* mrow = mask + (size_t)row * WORDS_PER_ROW;
    uint4 w = ((const uint4*)mrow)[lane];              // words 4*lane .. 4*lane+3
    uint32_t wa[4] = {w.x, w.y, w.z, w.w};
    int c = __popc(w.x) + __popc(w.y) + __popc(w.z) + __popc(w.w);

    // inclusive wave scan (width 64)
    int sum = c;
    for (int off = 1; off < 64; off <<= 1) {
        int v = __shfl_up(sum, off, 64);
        if (lane >= off) sum += v;
    }
    int excl = sum - c;
    if (lane == 63) {
        deg[row] = sum;
        dis[row] = rsqrtf((float)sum + EPS);
    }

    uint16_t* lrow = list + (size_t)row * MAXDEG;
    int base = lane * 128;                             // first bit index of this lane
    int pos = excl;
#pragma unroll
    for (int k = 0; k < 4; k++) {
        uint32_t m = wa[k];
        while (m) {
            int b = __ffs(m) - 1;
            m &= m - 1;
            if (pos < MAXDEG) lrow[pos] = (uint16_t)(base + k * 32 + b);
            pos++;
        }
    }
}

// ---------------------------------------------------------------------------
// Kernel 4: out[i][c] = b[c] + dis_i * sum_{j in row i} dis_j * z[j][c]
// (self loop is already in the list). One wave per row, 4 rows per block.
// Neighbor ids/weights preloaded to registers, broadcast via shfl -> no LDS,
// no syncthreads. z gathers are 256 B coalesced per iteration.
// ---------------------------------------------------------------------------
__global__ __launch_bounds__(256) void gcn_agg(const int* __restrict__ deg,
                                               const float* __restrict__ dis,
                                               const uint16_t* __restrict__ list,
                                               const uint16_t* __restrict__ z16,
                                               const float* __restrict__ bias,
                                               float* __restrict__ out) {
    int row  = blockIdx.x * 4 + (threadIdx.x >> 6);
    int lane = threadIdx.x & 63;
    int n = min(deg[row], MAXDEG);

    const uint16_t* lrow = list + (size_t)row * MAXDEG;
    int j0 = (lane < n)      ? lrow[lane]      : 0;
    int j1 = (64 + lane < n) ? lrow[64 + lane] : 0;
    float d0 = dis[j0];
    float d1 = dis[j1];

    const uint32_t* zu = (const uint32_t*)z16;
    float a0 = 0.f, a1 = 0.f;
    for (int m = 0; m < n; m++) {
        int jj; float dd;
        if (m < 64) { jj = __shfl(j0, m, 64);      dd = __shfl(d0, m, 64); }
        else        { jj = __shfl(j1, m - 64, 64); dd = __shfl(d1, m - 64, 64); }
        uint32_t u = zu[(size_t)jj * 64 + lane];   // coalesced 256 B
        a0 += dd * bf2f(u & 0xffffu);
        a1 += dd * bf2f(u >> 16);
    }

    float di = dis[row];
    float2 bv = ((const float2*)bias)[lane];
    float2 o;
    o.x = bv.x + di * a0;
    o.y = bv.y + di * a1;
    ((float2*)out)[(size_t)row * 64 + lane] = o;
}

// ---------------------------------------------------------------------------
extern "C" void kernel_launch(void* const* d_in, const int* in_sizes, int n_in,
                              void* d_out, int out_size, void* d_ws, size_t ws_size,
                              hipStream_t stream) {
    const float* x  = (const float*)d_in[0];
    const int*   ei = (const int*)d_in[1];
    const float* W  = (const float*)d_in[2];
    const float* b  = (const float*)d_in[3];
    float* out = (float*)d_out;

    int E = in_sizes[1] / 2;

    uint32_t* mask = (uint32_t*)d_ws;
    float*    dis  = (float*)   ((char*)d_ws + OFF_DIS);
    int*      deg  = (int*)     ((char*)d_ws + OFF_DEG);
    uint16_t* list = (uint16_t*)((char*)d_ws + OFF_LIST);
    uint16_t* z16  = (uint16_t*)((char*)d_ws + OFF_Z16);

    // zero mask + pre-set diagonal (self loops)
    gcn_fill<<<MASK_WORDS / 4 / 256, 256, 0, stream>>>(mask);

    // fire-and-forget scatter + xw, fused
    int sb = (E + 255) / 256;                          // 1024 scatter blocks
    int xb = N_NODES / XW_ROWS;                        // 256 xw blocks
    gcn_mid<<<sb + xb, 256, 0, stream>>>(ei, E, sb, mask, x, W, z16);

    // mask -> deg/dis/list (no atomics)
    gcn_extract<<<N_NODES / 4, 256, 0, stream>>>(mask, dis, deg, list);

    gcn_agg<<<N_NODES / 4, 256, 0, stream>>>(deg, dis, list, z16, b, out);
}